// Round 4
// baseline (1220.301 us; speedup 1.0000x reference)
//
#include <hip/hip_runtime.h>

#define M_ROWS 100000
#define MPAD   100096          // 782 * 128
#define FW     512
#define INMSG  1024
#define NTILE  4               // FW / 128 n-tiles
#define MTILE  782             // MPAD / 128 m-tiles
#define NWG    3128            // MTILE * NTILE, divisible by 8
#define CPX    391             // NWG / 8

typedef __attribute__((ext_vector_type(4))) float f32x4;
typedef __attribute__((ext_vector_type(8))) short bf16x8;

__device__ __forceinline__ unsigned short f2bf(float f) {
    unsigned u = __builtin_bit_cast(unsigned, f);
    u += 0x7fffu + ((u >> 16) & 1u);      // round-to-nearest-even
    return (unsigned short)(u >> 16);
}

__device__ __forceinline__ float selu_f(float x) {
    const float scale = 1.0507009873554805f;
    const float alpha = 1.6732632423543772f;
    return scale * (x > 0.0f ? x : alpha * expm1f(x));
}

// ---------------- weight convert: f32 -> bf16, vectorized ----------------
__global__ __launch_bounds__(256) void f32_to_bf16_k(
    const float* __restrict__ in, unsigned short* __restrict__ out, int n4)
{
    int i = blockIdx.x * 256 + threadIdx.x;
    if (i < n4) {
        f32x4 x = ((const f32x4*)in)[i];
        ushort4 o;
        o.x = f2bf(x[0]); o.y = f2bf(x[1]); o.z = f2bf(x[2]); o.w = f2bf(x[3]);
        ((ushort4*)out)[i] = o;
    }
}

// ------- fused edge-encoder + gather + concat + LayerNorm -> bf16 msg -------
__global__ __launch_bounds__(256) void build_msg_k(
    const float* __restrict__ v, const float* __restrict__ e_rel,
    const int* __restrict__ idx, const float* __restrict__ v_skip,
    const float* __restrict__ We, const float* __restrict__ be,
    const float* __restrict__ ln_g, const float* __restrict__ ln_b,
    unsigned short* __restrict__ msg)
{
    const int r = blockIdx.x;
    const int t = threadIdx.x;

    f32x4 val;
    if (t < 128) {                       // e_enc = -e * We[:,0] + be
        float e = e_rel[r];
        f32x4 we = ((const f32x4*)We)[t];
        f32x4 bb = ((const f32x4*)be)[t];
        val = (-e) * we + bb;
    } else if (t < 192) {                // gathered v row
        long vr = (long)idx[r] * 256;
        val = ((const f32x4*)(v + vr))[t - 128];
    } else {                             // v_skip row
        val = ((const f32x4*)(v_skip + (long)r * 256))[t - 192];
    }

    float s = val[0] + val[1] + val[2] + val[3];
    float q = val[0]*val[0] + val[1]*val[1] + val[2]*val[2] + val[3]*val[3];
    #pragma unroll
    for (int off = 32; off; off >>= 1) {
        s += __shfl_down(s, off, 64);
        q += __shfl_down(q, off, 64);
    }
    __shared__ float red[8];
    const int lane = t & 63, wv = t >> 6;
    if (lane == 0) { red[wv] = s; red[4 + wv] = q; }
    __syncthreads();
    float S  = red[0] + red[1] + red[2] + red[3];
    float Q  = red[4] + red[5] + red[6] + red[7];
    float mu = S * (1.0f / 1024.0f);
    float var = Q * (1.0f / 1024.0f) - mu * mu;
    float rs = rsqrtf(var + 1e-5f);

    f32x4 g = ((const f32x4*)ln_g)[t];
    f32x4 b = ((const f32x4*)ln_b)[t];
    ushort4 o;
    o.x = f2bf((val[0] - mu) * rs * g[0] + b[0]);
    o.y = f2bf((val[1] - mu) * rs * g[1] + b[1]);
    o.z = f2bf((val[2] - mu) * rs * g[2] + b[2]);
    o.w = f2bf((val[3] - mu) * rs * g[3] + b[3]);
    ((ushort4*)(msg + (long)r * INMSG))[t] = o;
}

// ---------------- bf16 MFMA GEMM + bias + SELU ----------------
// C[m][n] = sum_k A[m][k] * W[n][k];  A: [MPAD][K] bf16, W: [512][K] bf16
// 128x128 tile, BK=64, 4 waves 2x2, wave = 64x64 (4x4 of 16x16x32).
//
// R3 changes:
//  * 1D grid, n-tile fastest + m204 bijective XCD chunking: concurrent
//    blocks within an XCD share A-panels -> A fetched ~once (was 4x).
//  * T3-minimum 2-phase double-buffered pipeline: STAGE(next) issued
//    BEFORE compute(current); ONE __syncthreads() per K-tile (its implicit
//    vmcnt(0)+lgkmcnt(0) covers both hand-offs). HBM latency hides under
//    the 32 MFMAs of the current tile.
//  * T2 XOR-swizzle kept (conflicts measured 0): LDS (row,g) holds global
//    granule g ^ (row&7); staging pre-swizzles the GLOBAL source granule
//    ((lane&7)^(lane>>3)); reads use g = G ^ (row&7).
template<int K, bool LAST>
__global__ __launch_bounds__(256) void gemm_selu_k(
    const unsigned short* __restrict__ A,
    const unsigned short* __restrict__ W,
    const float* __restrict__ bias,
    void* __restrict__ out, int M)
{
    __shared__ __align__(16) unsigned short ldsA[2][128][64];
    __shared__ __align__(16) unsigned short ldsB[2][128][64];

    const int tid  = threadIdx.x;
    const int lane = tid & 63;
    const int w    = tid >> 6;
    const int wr   = w >> 1, wc = w & 1;

    // XCD-chunked bijective swizzle (nwg = 3128 = 8*391), n-tile fastest
    const int b  = blockIdx.x;
    const int l  = (b & 7) * CPX + (b >> 3);
    const long m0 = (long)(l >> 2) * 128;     // l / NTILE
    const int  n0 = (l & 3) * 128;            // l % NTILE

    f32x4 acc[4][4] = {};

    const int lr = lane >> 3;                      // row within 8-row chunk
    const int lc = ((lane & 7) ^ lr) * 8;          // PRE-SWIZZLED global granule
    const int l15 = lane & 15;
    const int hi  = lane >> 4;
    const int l7  = lane & 7;

    const unsigned short* Abase = A + (m0 + w * 8 + lr) * K + lc;
    const unsigned short* Bbase = W + (long)(n0 + w * 8 + lr) * K + lc;

    auto stage = [&](int s, int t) {
        const int k0 = t * 64;
        #pragma unroll
        for (int i = 0; i < 4; ++i) {
            const int rowoff = i * 32 + w * 8;
            __builtin_amdgcn_global_load_lds(
                (const __attribute__((address_space(1))) unsigned int*)(Abase + (long)i * 32 * K + k0),
                (__attribute__((address_space(3))) unsigned int*)&ldsA[s][rowoff][0],
                16, 0, 0);
            __builtin_amdgcn_global_load_lds(
                (const __attribute__((address_space(1))) unsigned int*)(Bbase + (long)i * 32 * K + k0),
                (__attribute__((address_space(3))) unsigned int*)&ldsB[s][rowoff][0],
                16, 0, 0);
        }
    };

    constexpr int NT_K = K / 64;
    stage(0, 0);
    __syncthreads();                       // vmcnt(0): buf0 ready

    int cur = 0;
    for (int t = 0; t < NT_K; ++t) {
        if (t + 1 < NT_K) stage(cur ^ 1, t + 1);   // prefetch next tile

        #pragma unroll
        for (int kk = 0; kk < 2; ++kk) {
            bf16x8 af[4], bfr[4];
            const int g = (kk * 4 + hi) ^ l7;      // swizzled read granule
            #pragma unroll
            for (int mf = 0; mf < 4; ++mf)
                af[mf] = *(const bf16x8*)&ldsA[cur][wr*64 + mf*16 + l15][g * 8];
            #pragma unroll
            for (int nf = 0; nf < 4; ++nf)
                bfr[nf] = *(const bf16x8*)&ldsB[cur][wc*64 + nf*16 + l15][g * 8];
            #pragma unroll
            for (int mf = 0; mf < 4; ++mf)
                #pragma unroll
                for (int nf = 0; nf < 4; ++nf)
                    acc[mf][nf] = __builtin_amdgcn_mfma_f32_16x16x32_bf16(
                        af[mf], bfr[nf], acc[mf][nf], 0, 0, 0);
        }
        __syncthreads();   // next buf staged (vmcnt0) + this buf's reads done (lgkmcnt0)
        cur ^= 1;
    }

    // epilogue: bias + SELU + store (guard r < M)
    #pragma unroll
    for (int nf = 0; nf < 4; ++nf) {
        const int col = n0 + wc*64 + nf*16 + l15;
        const float bv = bias[col];
        #pragma unroll
        for (int mf = 0; mf < 4; ++mf) {
            const long row = m0 + wr*64 + mf*16 + hi * 4;
            #pragma unroll
            for (int i = 0; i < 4; ++i) {
                const long r = row + i;
                if (r < M) {
                    float x = acc[mf][nf][i] + bv;
                    float sv = selu_f(x);
                    if (LAST) ((float*)out)[r * FW + col] = sv;
                    else      ((unsigned short*)out)[r * FW + col] = f2bf(sv);
                }
            }
        }
    }
}

extern "C" void kernel_launch(void* const* d_in, const int* in_sizes, int n_in,
                              void* d_out, int out_size, void* d_ws, size_t ws_size,
                              hipStream_t stream) {
    const float* v      = (const float*)d_in[0];
    const float* e_rel  = (const float*)d_in[1];
    const int*   idx    = (const int*)d_in[2];
    const float* v_skip = (const float*)d_in[3];
    const float* We     = (const float*)d_in[4];
    const float* be     = (const float*)d_in[5];
    const float* ln_g   = (const float*)d_in[6];
    const float* ln_b   = (const float*)d_in[7];
    const float* W0 = (const float*)d_in[8];  const float* b0 = (const float*)d_in[9];
    const float* W1 = (const float*)d_in[10]; const float* b1 = (const float*)d_in[11];
    const float* W2 = (const float*)d_in[12]; const float* b2 = (const float*)d_in[13];
    const float* W3 = (const float*)d_in[14]; const float* b3 = (const float*)d_in[15];

    char* ws = (char*)d_ws;
    const size_t MSG_BYTES = (size_t)MPAD * INMSG * 2;   // 204,996,608
    const size_t H_BYTES   = (size_t)MPAD * FW * 2;      // 102,498,304
    unsigned short* msg = (unsigned short*)ws;
    unsigned short* W0b = (unsigned short*)(ws + MSG_BYTES);
    unsigned short* W1b = W0b + 1024 * 512;
    unsigned short* W2b = W1b + 512 * 512;
    unsigned short* W3b = W2b + 512 * 512;
    unsigned short* h0  = (unsigned short*)d_out;        // d_out as bf16 scratch
    unsigned short* h1  = (unsigned short*)ws;           // msg dead after L0
    unsigned short* h2  = (unsigned short*)(ws + H_BYTES);

    f32_to_bf16_k<<<dim3(512), 256, 0, stream>>>(W0, W0b, 1024 * 512 / 4);
    f32_to_bf16_k<<<dim3(256), 256, 0, stream>>>(W1, W1b, 512 * 512 / 4);
    f32_to_bf16_k<<<dim3(256), 256, 0, stream>>>(W2, W2b, 512 * 512 / 4);
    f32_to_bf16_k<<<dim3(256), 256, 0, stream>>>(W3, W3b, 512 * 512 / 4);

    build_msg_k<<<dim3(M_ROWS), 256, 0, stream>>>(v, e_rel, idx, v_skip,
                                                  We, be, ln_g, ln_b, msg);

    dim3 ggrid(NWG);
    gemm_selu_k<1024, false><<<ggrid, 256, 0, stream>>>(msg, W0b, b0, h0, M_ROWS);
    gemm_selu_k<512,  false><<<ggrid, 256, 0, stream>>>(h0,  W1b, b1, h1, M_ROWS);
    gemm_selu_k<512,  false><<<ggrid, 256, 0, stream>>>(h1,  W2b, b2, h2, M_ROWS);
    gemm_selu_k<512,  true ><<<ggrid, 256, 0, stream>>>(h2,  W3b, b3, d_out, M_ROWS);
}

// Round 5
// 993.370 us; speedup vs baseline: 1.2284x; 1.2284x over previous
//
#include <hip/hip_runtime.h>

#define M_ROWS 100000
#define MPAD   100096          // 1564 * 64
#define FW     512
#define INMSG  1024
#define ROWS   64
#define NBLK   1564            // MPAD / ROWS

typedef __attribute__((ext_vector_type(4))) float f32x4;
typedef __attribute__((ext_vector_type(8))) short bf16x8;

__device__ __forceinline__ unsigned short f2bf(float f) {
    unsigned u = __builtin_bit_cast(unsigned, f);
    u += 0x7fffu + ((u >> 16) & 1u);      // round-to-nearest-even
    return (unsigned short)(u >> 16);
}

// cheap SELU: single v_exp_f32 instead of expm1f's long sequence
__device__ __forceinline__ float selu_f(float x) {
    const float scale = 1.0507009873554805f;
    const float alpha = 1.6732632423543772f;
    float e = __expf(x);                  // unused (but finite-select-safe) when x>0
    return scale * (x > 0.0f ? x : alpha * (e - 1.0f));
}

// ---------------- weight convert: f32 -> bf16, vectorized ----------------
__global__ __launch_bounds__(256) void f32_to_bf16_k(
    const float* __restrict__ in, unsigned short* __restrict__ out, int n4)
{
    int i = blockIdx.x * 256 + threadIdx.x;
    if (i < n4) {
        f32x4 x = ((const f32x4*)in)[i];
        ushort4 o;
        o.x = f2bf(x[0]); o.y = f2bf(x[1]); o.z = f2bf(x[2]); o.w = f2bf(x[3]);
        ((ushort4*)out)[i] = o;
    }
}

// ------- fused edge-encoder + gather + concat + LayerNorm -> bf16 msg -------
__global__ __launch_bounds__(256) void build_msg_k(
    const float* __restrict__ v, const float* __restrict__ e_rel,
    const int* __restrict__ idx, const float* __restrict__ v_skip,
    const float* __restrict__ We, const float* __restrict__ be,
    const float* __restrict__ ln_g, const float* __restrict__ ln_b,
    unsigned short* __restrict__ msg)
{
    const int r = blockIdx.x;
    const int t = threadIdx.x;

    f32x4 val;
    if (t < 128) {                       // e_enc = -e * We[:,0] + be
        float e = e_rel[r];
        f32x4 we = ((const f32x4*)We)[t];
        f32x4 bb = ((const f32x4*)be)[t];
        val = (-e) * we + bb;
    } else if (t < 192) {                // gathered v row
        long vr = (long)idx[r] * 256;
        val = ((const f32x4*)(v + vr))[t - 128];
    } else {                             // v_skip row
        val = ((const f32x4*)(v_skip + (long)r * 256))[t - 192];
    }

    float s = val[0] + val[1] + val[2] + val[3];
    float q = val[0]*val[0] + val[1]*val[1] + val[2]*val[2] + val[3]*val[3];
    #pragma unroll
    for (int off = 32; off; off >>= 1) {
        s += __shfl_down(s, off, 64);
        q += __shfl_down(q, off, 64);
    }
    __shared__ float red[8];
    const int lane = t & 63, wv = t >> 6;
    if (lane == 0) { red[wv] = s; red[4 + wv] = q; }
    __syncthreads();
    float S  = red[0] + red[1] + red[2] + red[3];
    float Q  = red[4] + red[5] + red[6] + red[7];
    float mu = S * (1.0f / 1024.0f);
    float var = Q * (1.0f / 1024.0f) - mu * mu;
    float rs = rsqrtf(var + 1e-5f);

    f32x4 g = ((const f32x4*)ln_g)[t];
    f32x4 b = ((const f32x4*)ln_b)[t];
    ushort4 o;
    o.x = f2bf((val[0] - mu) * rs * g[0] + b[0]);
    o.y = f2bf((val[1] - mu) * rs * g[1] + b[1]);
    o.z = f2bf((val[2] - mu) * rs * g[2] + b[2]);
    o.w = f2bf((val[3] - mu) * rs * g[3] + b[3]);
    ((ushort4*)(msg + (long)r * INMSG))[t] = o;
}

// ---------------- fused 4-layer MLP ----------------
// Block: 64-row stripe. 512 thr = 8 waves, 2(m) x 4(n); wave tile 32 x 64
// per 256-col half -> acc0 (cols 0..255), acc1 (cols 256..511).
// hb [64][512] bf16 holds the activations between layers (in LDS only).
// Weights stream L2 -> Wb[2][256][64] double-buffered, 2 phases per k-tile.
// All [*][64]-row tiles use the XOR-granule swizzle (LDS granule g holds
// global granule g ^ (row&7)); hb uses the same swizzle applied on its
// register-sourced ds_write side. (Verified-0-conflict pattern from R3.)
__global__ __launch_bounds__(512) void fused_mlp_k(
    const unsigned short* __restrict__ msg,
    const unsigned short* __restrict__ W0b, const float* __restrict__ b0,
    const unsigned short* __restrict__ W1b, const float* __restrict__ b1,
    const unsigned short* __restrict__ W2b, const float* __restrict__ b2,
    const unsigned short* __restrict__ W3b, const float* __restrict__ b3,
    float* __restrict__ out, int M)
{
    __shared__ __align__(16) unsigned short Ab[2][64][64];    // 16 KB
    __shared__ __align__(16) unsigned short Wb[2][256][64];   // 64 KB
    __shared__ __align__(16) unsigned short hb[64][512];      // 64 KB

    const int tid  = threadIdx.x;
    const int lane = tid & 63;
    const int w    = tid >> 6;
    const int wm   = w >> 2, wn = w & 3;
    const int l15  = lane & 15, hi = lane >> 4;
    const long m0  = (long)blockIdx.x * ROWS;

    const int srow = tid >> 3;                 // staging row 0..63
    const int sg   = (tid & 7) ^ (srow & 7);   // pre-swizzled src granule

    f32x4 acc0[2][4], acc1[2][4];

    auto stageW = [&](const unsigned short* Wl, int half, int kt, int buf, int Kd) {
        #pragma unroll
        for (int i = 0; i < 4; ++i) {
            const unsigned short* src =
                Wl + (long)(half * 256 + i * 64 + srow) * Kd + kt * 64 + sg * 8;
            __builtin_amdgcn_global_load_lds(
                (const __attribute__((address_space(1))) unsigned int*)src,
                (__attribute__((address_space(3))) unsigned int*)
                    ((unsigned short*)&Wb[buf][0][0] + i * 4096 + w * 512),
                16, 0, 0);
        }
    };
    auto stageA = [&](int kt, int buf) {
        const unsigned short* src = msg + (m0 + srow) * INMSG + kt * 64 + sg * 8;
        __builtin_amdgcn_global_load_lds(
            (const __attribute__((address_space(1))) unsigned int*)src,
            (__attribute__((address_space(3))) unsigned int*)
                ((unsigned short*)&Ab[buf][0][0] + w * 512),
            16, 0, 0);
    };
    auto zero_acc = [&]() {
        #pragma unroll
        for (int mf = 0; mf < 2; ++mf)
            #pragma unroll
            for (int nf = 0; nf < 4; ++nf) { acc0[mf][nf] = {}; acc1[mf][nf] = {}; }
    };

    auto compute_l0 = [&](f32x4 (&ac)[2][4], int abuf, int wbuf) {
        #pragma unroll
        for (int kk = 0; kk < 2; ++kk) {
            bf16x8 af[2], bq[4];
            #pragma unroll
            for (int mf = 0; mf < 2; ++mf) {
                const int arow = wm * 32 + mf * 16 + l15;
                const int ag = (kk * 4 + hi) ^ (arow & 7);
                af[mf] = *(const bf16x8*)&Ab[abuf][arow][ag * 8];
            }
            #pragma unroll
            for (int nf = 0; nf < 4; ++nf) {
                const int brow = wn * 64 + nf * 16 + l15;
                const int bg = (kk * 4 + hi) ^ (brow & 7);
                bq[nf] = *(const bf16x8*)&Wb[wbuf][brow][bg * 8];
            }
            #pragma unroll
            for (int mf = 0; mf < 2; ++mf)
                #pragma unroll
                for (int nf = 0; nf < 4; ++nf)
                    ac[mf][nf] = __builtin_amdgcn_mfma_f32_16x16x32_bf16(
                        af[mf], bq[nf], ac[mf][nf], 0, 0, 0);
        }
    };

    auto compute_h = [&](f32x4 (&ac)[2][4], int t, int wbuf) {
        #pragma unroll
        for (int kk = 0; kk < 2; ++kk) {
            bf16x8 af[2], bq[4];
            #pragma unroll
            for (int mf = 0; mf < 2; ++mf) {
                const int arow = wm * 32 + mf * 16 + l15;
                const int ag = (t * 8 + kk * 4 + hi) ^ (arow & 7);
                af[mf] = *(const bf16x8*)&hb[arow][ag * 8];
            }
            #pragma unroll
            for (int nf = 0; nf < 4; ++nf) {
                const int brow = wn * 64 + nf * 16 + l15;
                const int bg = (kk * 4 + hi) ^ (brow & 7);
                bq[nf] = *(const bf16x8*)&Wb[wbuf][brow][bg * 8];
            }
            #pragma unroll
            for (int mf = 0; mf < 2; ++mf)
                #pragma unroll
                for (int nf = 0; nf < 4; ++nf)
                    ac[mf][nf] = __builtin_amdgcn_mfma_f32_16x16x32_bf16(
                        af[mf], bq[nf], ac[mf][nf], 0, 0, 0);
        }
    };

    // write one half's activations (SELU'd bf16) into hb, swizzled
    auto write_half = [&](f32x4 (&ac)[2][4], int h, const float* bl) {
        #pragma unroll
        for (int nf = 0; nf < 4; ++nf) {
            const int col = h * 256 + wn * 64 + nf * 16 + l15;
            const float bv = bl[col];
            #pragma unroll
            for (int mf = 0; mf < 2; ++mf) {
                const int row = wm * 32 + mf * 16 + hi * 4;
                #pragma unroll
                for (int i = 0; i < 4; ++i) {
                    const int r = row + i;
                    const int g = (col >> 3) ^ (r & 7);
                    hb[r][g * 8 + (col & 7)] = f2bf(selu_f(ac[mf][nf][i] + bv));
                }
            }
        }
    };

    auto write_out_half = [&](f32x4 (&ac)[2][4], int h, const float* bl) {
        #pragma unroll
        for (int nf = 0; nf < 4; ++nf) {
            const int col = h * 256 + wn * 64 + nf * 16 + l15;
            const float bv = bl[col];
            #pragma unroll
            for (int mf = 0; mf < 2; ++mf) {
                const long row = m0 + wm * 32 + mf * 16 + hi * 4;
                #pragma unroll
                for (int i = 0; i < 4; ++i) {
                    const long r = row + i;
                    if (r < M) out[r * FW + col] = selu_f(ac[mf][nf][i] + bv);
                }
            }
        }
    };

    // ---------------- layer 0 (K = 1024, A from msg) ----------------
    zero_acc();
    stageW(W0b, 0, 0, 0, INMSG);
    stageA(0, 0);
    __syncthreads();
    for (int t = 0; t < 16; ++t) {
        stageW(W0b, 1, t, 1, INMSG);            // (t, half1) -> Wb[1]
        compute_l0(acc0, t & 1, 0);
        __syncthreads();
        if (t < 15) { stageW(W0b, 0, t + 1, 0, INMSG); stageA(t + 1, (t + 1) & 1); }
        compute_l0(acc1, t & 1, 1);
        __syncthreads();
    }
    write_half(acc0, 0, b0);
    write_half(acc1, 1, b0);

    // ---------------- hidden layers (K = 512, A from hb) ----------------
    auto hidden = [&](const unsigned short* Wl) {
        zero_acc();
        stageW(Wl, 0, 0, 0, FW);
        __syncthreads();       // orders prior hb writes before this layer's reads
        for (int t = 0; t < 8; ++t) {
            stageW(Wl, 1, t, 1, FW);
            compute_h(acc0, t, 0);
            __syncthreads();
            if (t < 7) stageW(Wl, 0, t + 1, 0, FW);
            compute_h(acc1, t, 1);
            __syncthreads();
        }
    };

    hidden(W1b); write_half(acc0, 0, b1); write_half(acc1, 1, b1);
    hidden(W2b); write_half(acc0, 0, b2); write_half(acc1, 1, b2);
    hidden(W3b); write_out_half(acc0, 0, b3); write_out_half(acc1, 1, b3);
}

extern "C" void kernel_launch(void* const* d_in, const int* in_sizes, int n_in,
                              void* d_out, int out_size, void* d_ws, size_t ws_size,
                              hipStream_t stream) {
    const float* v      = (const float*)d_in[0];
    const float* e_rel  = (const float*)d_in[1];
    const int*   idx    = (const int*)d_in[2];
    const float* v_skip = (const float*)d_in[3];
    const float* We     = (const float*)d_in[4];
    const float* be     = (const float*)d_in[5];
    const float* ln_g   = (const float*)d_in[6];
    const float* ln_b   = (const float*)d_in[7];
    const float* W0 = (const float*)d_in[8];  const float* b0 = (const float*)d_in[9];
    const float* W1 = (const float*)d_in[10]; const float* b1 = (const float*)d_in[11];
    const float* W2 = (const float*)d_in[12]; const float* b2 = (const float*)d_in[13];
    const float* W3 = (const float*)d_in[14]; const float* b3 = (const float*)d_in[15];

    char* ws = (char*)d_ws;
    const size_t MSG_BYTES = (size_t)MPAD * INMSG * 2;   // 204,996,608
    unsigned short* msg = (unsigned short*)ws;
    unsigned short* W0b = (unsigned short*)(ws + MSG_BYTES);
    unsigned short* W1b = W0b + 1024 * 512;
    unsigned short* W2b = W1b + 512 * 512;
    unsigned short* W3b = W2b + 512 * 512;

    f32_to_bf16_k<<<dim3(512), 256, 0, stream>>>(W0, W0b, 1024 * 512 / 4);
    f32_to_bf16_k<<<dim3(256), 256, 0, stream>>>(W1, W1b, 512 * 512 / 4);
    f32_to_bf16_k<<<dim3(256), 256, 0, stream>>>(W2, W2b, 512 * 512 / 4);
    f32_to_bf16_k<<<dim3(256), 256, 0, stream>>>(W3, W3b, 512 * 512 / 4);

    build_msg_k<<<dim3(M_ROWS), 256, 0, stream>>>(v, e_rel, idx, v_skip,
                                                  We, be, ln_g, ln_b, msg);

    fused_mlp_k<<<dim3(NBLK), 512, 0, stream>>>(msg,
                                                W0b, b0, W1b, b1, W2b, b2, W3b, b3,
                                                (float*)d_out, M_ROWS);
}